// Round 1
// baseline (821.799 us; speedup 1.0000x reference)
//
#include <hip/hip_runtime.h>
#include <stdint.h>

#define F_DIM 256
#define O_DIM 24
#define BM 128
#define BN 128
#define BK 16
#define NSPLIT 64
#define LDA (BM + 4)   // pad to break power-of-2 bank strides

__device__ __forceinline__ unsigned int orderable(float s) {
    unsigned int b = __float_as_uint(s);
    // map float ordering onto unsigned ordering
    return (b & 0x80000000u) ? ~b : (b | 0x80000000u);
}

__global__ void init_best_kernel(unsigned long long* best, int B) {
    int i = blockIdx.x * blockDim.x + threadIdx.x;
    if (i < B) best[i] = 0xFFFFFFFFFFFFFFFFull;
}

// one wave (64 lanes) per train row: t2[n] = sum_f X[n][f]^2
__global__ void t2_kernel(const float* __restrict__ X, float* __restrict__ t2, int N) {
    int tid  = threadIdx.x;
    int row  = blockIdx.x * 4 + (tid >> 6);
    int lane = tid & 63;
    if (row >= N) return;
    float4 v = ((const float4*)(X + (size_t)row * F_DIM))[lane];
    float s = v.x * v.x + v.y * v.y + v.z * v.z + v.w * v.w;
    #pragma unroll
    for (int off = 32; off > 0; off >>= 1) s += __shfl_down(s, off, 64);
    if (lane == 0) t2[row] = s;
}

// Main: fused GEMM (scores = t2[n] - 2 * x·Xt[n]) + running argmin
__global__ __launch_bounds__(256) void knn_main(
    const float* __restrict__ Xq, const float* __restrict__ Xt,
    const float* __restrict__ t2, unsigned long long* __restrict__ best,
    int N)
{
    __shared__ float As[BK][LDA];
    __shared__ float Bs[BK][LDA];
    __shared__ unsigned long long red[BM][17];

    const int tid = threadIdx.x;
    const int tx = tid & 15;     // n dimension
    const int ty = tid >> 4;     // m dimension
    const int m0 = blockIdx.y * BM;

    const int CHUNK = (N + NSPLIT - 1) / NSPLIT;
    const int n0c = blockIdx.x * CHUNK;
    const int n1c = min(N, n0c + CHUNK);

    unsigned long long bestv[8];
    #pragma unroll
    for (int i = 0; i < 8; ++i) bestv[i] = 0xFFFFFFFFFFFFFFFFull;

    // staging mapping: each thread loads one float4 per half-tile
    const int srow  = tid >> 2;        // 0..63
    const int scol4 = (tid & 3) * 4;   // 0,4,8,12

    for (int nt = n0c; nt < n1c; nt += BN) {
        float acc[8][8];
        #pragma unroll
        for (int i = 0; i < 8; ++i)
            #pragma unroll
            for (int j = 0; j < 8; ++j) acc[i][j] = 0.f;

        for (int k0 = 0; k0 < F_DIM; k0 += BK) {
            #pragma unroll
            for (int h = 0; h < 2; ++h) {
                int row = h * 64 + srow;
                float4 av = *(const float4*)(Xq + (size_t)(m0 + row) * F_DIM + k0 + scol4);
                As[scol4 + 0][row] = av.x;
                As[scol4 + 1][row] = av.y;
                As[scol4 + 2][row] = av.z;
                As[scol4 + 3][row] = av.w;
                int n = nt + row;
                float4 bv = make_float4(0.f, 0.f, 0.f, 0.f);
                if (n < n1c) bv = *(const float4*)(Xt + (size_t)n * F_DIM + k0 + scol4);
                Bs[scol4 + 0][row] = bv.x;
                Bs[scol4 + 1][row] = bv.y;
                Bs[scol4 + 2][row] = bv.z;
                Bs[scol4 + 3][row] = bv.w;
            }
            __syncthreads();
            #pragma unroll
            for (int k = 0; k < BK; ++k) {
                float4 a0 = *(const float4*)&As[k][ty * 4];
                float4 a1 = *(const float4*)&As[k][64 + ty * 4];
                float4 b0 = *(const float4*)&Bs[k][tx * 4];
                float4 b1 = *(const float4*)&Bs[k][64 + tx * 4];
                float am[8] = {a0.x, a0.y, a0.z, a0.w, a1.x, a1.y, a1.z, a1.w};
                float bn[8] = {b0.x, b0.y, b0.z, b0.w, b1.x, b1.y, b1.z, b1.w};
                #pragma unroll
                for (int i = 0; i < 8; ++i)
                    #pragma unroll
                    for (int j = 0; j < 8; ++j)
                        acc[i][j] = fmaf(am[i], bn[j], acc[i][j]);
            }
            __syncthreads();
        }

        // epilogue: score = t2[n] - 2*cross, update running packed min
        #pragma unroll
        for (int j = 0; j < 8; ++j) {
            int nl = (j < 4) ? (tx * 4 + j) : (64 + tx * 4 + (j - 4));
            int n = nt + nl;
            if (n < n1c) {
                float t2v = t2[n];
                #pragma unroll
                for (int i = 0; i < 8; ++i) {
                    float score = fmaf(-2.f, acc[i][j], t2v);
                    unsigned long long p =
                        ((unsigned long long)orderable(score) << 32) | (unsigned int)n;
                    bestv[i] = (p < bestv[i]) ? p : bestv[i];
                }
            }
        }
    }

    // block-level reduce across the 16 tx columns, then one atomic per query
    #pragma unroll
    for (int i = 0; i < 8; ++i) {
        int ml = (i < 4) ? (ty * 4 + i) : (64 + ty * 4 + (i - 4));
        red[ml][tx] = bestv[i];
    }
    __syncthreads();
    if (tid < BM) {
        unsigned long long b = red[tid][0];
        #pragma unroll
        for (int t = 1; t < 16; ++t) {
            unsigned long long v = red[tid][t];
            b = (v < b) ? v : b;
        }
        atomicMin(&best[m0 + tid], b);
    }
}

__global__ void gather_kernel(const float* __restrict__ Y,
                              const unsigned long long* __restrict__ best,
                              float* __restrict__ out, int B) {
    int gid = blockIdx.x * blockDim.x + threadIdx.x;
    int total = B * O_DIM;
    if (gid >= total) return;
    int b = gid / O_DIM;
    int o = gid - b * O_DIM;
    unsigned int n = (unsigned int)(best[b] & 0xFFFFFFFFull);
    out[gid] = Y[(size_t)n * O_DIM + o];
}

extern "C" void kernel_launch(void* const* d_in, const int* in_sizes, int n_in,
                              void* d_out, int out_size, void* d_ws, size_t ws_size,
                              hipStream_t stream) {
    const float* x  = (const float*)d_in[0];
    const float* Xt = (const float*)d_in[1];
    const float* Yt = (const float*)d_in[2];
    float* out = (float*)d_out;

    const int B = in_sizes[0] / F_DIM;   // 2048
    const int N = in_sizes[1] / F_DIM;   // 50000

    float* t2 = (float*)d_ws;
    size_t t2_bytes = ((size_t)N * sizeof(float) + 255) & ~(size_t)255;
    unsigned long long* best = (unsigned long long*)((char*)d_ws + t2_bytes);

    init_best_kernel<<<(B + 255) / 256, 256, 0, stream>>>(best, B);
    t2_kernel<<<(N + 3) / 4, 256, 0, stream>>>(Xt, t2, N);

    dim3 grid(NSPLIT, B / BM);
    knn_main<<<grid, 256, 0, stream>>>(x, Xt, t2, best, N);

    int total = B * O_DIM;
    gather_kernel<<<(total + 255) / 256, 256, 0, stream>>>(Yt, best, out, B);
}

// Round 2
// 546.722 us; speedup vs baseline: 1.5031x; 1.5031x over previous
//
#include <hip/hip_runtime.h>
#include <stdint.h>

typedef unsigned short u16;
typedef unsigned int   u32;
typedef unsigned long long u64;

#define F_DIM 256
#define O_DIM 24
#define MARGIN 12.0f
#define CAND_CAP (1u << 21)   // 2M candidates * 4B = 8 MB

#define AS1 __attribute__((address_space(1)))
#define AS3 __attribute__((address_space(3)))

typedef __bf16 bf16x8 __attribute__((ext_vector_type(8)));
typedef float  f32x4  __attribute__((ext_vector_type(4)));

__device__ __forceinline__ u32 ordf(float s) {
    u32 b = __float_as_uint(s);
    return (b & 0x80000000u) ? ~b : (b | 0x80000000u);
}
__device__ __forceinline__ float unordf(u32 u) {
    u32 b = (u & 0x80000000u) ? (u & 0x7FFFFFFFu) : ~u;
    return __uint_as_float(b);
}
__device__ __forceinline__ u16 f2bf(float f) {   // round-to-nearest-even
    u32 u = __float_as_uint(f);
    u32 r = (u + 0x7FFFu + ((u >> 16) & 1u)) >> 16;
    return (u16)r;
}

// ---------------- init ----------------
__global__ void init_kernel(u64* best, u32* rowminU, u32* cand_cnt, int B) {
    int i = blockIdx.x * blockDim.x + threadIdx.x;
    if (i < B) { best[i] = ~0ull; rowminU[i] = 0xFFFFFFFFu; }
    if (i == 0) *cand_cnt = 0u;
}

// ---------------- t2 = ||Xt_row||^2 (fp32 exact-ish), pads get +huge ----------------
__global__ void t2_kernel(const float* __restrict__ X, float* __restrict__ t2,
                          int N, int Npad) {
    int tid = threadIdx.x;
    int row = blockIdx.x * 4 + (tid >> 6);
    int lane = tid & 63;
    if (row >= Npad) return;
    if (row >= N) { if (lane == 0) t2[row] = 1e30f; return; }
    float4 v = ((const float4*)(X + (size_t)row * F_DIM))[lane];
    float s = v.x * v.x + v.y * v.y + v.z * v.z + v.w * v.w;
    #pragma unroll
    for (int off = 32; off > 0; off >>= 1) s += __shfl_down(s, off, 64);
    if (lane == 0) t2[row] = s;
}

// ---------------- fp32 -> bf16, pre-swizzled into MFMA fragment order ----------------
// dst layout: [tile128][kstep(8)][sub(8)][lane(64)][j(8)]
//   row = tile*128 + sub*16 + (lane&15);  k = kstep*32 + (lane>>4)*8 + j
__global__ void convert_swizzle(const float* __restrict__ src, u16* __restrict__ dst,
                                int rows_valid, int total_units) {
    int u = blockIdx.x * blockDim.x + threadIdx.x;
    if (u >= total_units) return;
    int L   = u & 63;
    int sub = (u >> 6) & 7;
    int ks  = (u >> 9) & 7;
    int t   = u >> 12;
    int row = t * 128 + sub * 16 + (L & 15);
    int k0  = ks * 32 + (L >> 4) * 8;
    uint4 o = make_uint4(0, 0, 0, 0);
    if (row < rows_valid) {
        const float* p = src + (size_t)row * F_DIM + k0;
        float4 a = *(const float4*)p;
        float4 b = *(const float4*)(p + 4);
        o.x = ((u32)f2bf(a.y) << 16) | f2bf(a.x);
        o.y = ((u32)f2bf(a.w) << 16) | f2bf(a.z);
        o.z = ((u32)f2bf(b.y) << 16) | f2bf(b.x);
        o.w = ((u32)f2bf(b.w) << 16) | f2bf(b.z);
    }
    *(uint4*)(dst + (size_t)u * 8) = o;
}

// ---------------- main fused bf16-MFMA GEMM + margin candidate capture ----------------
__global__ __launch_bounds__(256, 2) void knn_mfma(
    const u16* __restrict__ xbf, const u16* __restrict__ xtbf,
    const float* __restrict__ t2, u32* __restrict__ rowminU,
    u32* __restrict__ cand_cnt, u32* __restrict__ cands,
    int ntiles, int tpc)
{
    __shared__ u16 sA[32768];     // 64 KB: full A tile (128 x 256), fragment order
    __shared__ u16 sB[2][4096];   // 2 x 8 KB: one kstep of B, double buffered

    const int tid = threadIdx.x;
    const int L = tid & 63, w = tid >> 6;
    const int mq = w >> 1, nq = w & 1;
    const int mt = blockIdx.x;            // m-tile 0..15
    const int chunk = blockIdx.y;
    const int t0 = chunk * tpc;
    const int t1 = min(t0 + tpc, ntiles);

    // stage A tile once (64 KB), async global->LDS, 16B units
    {
        const AS1 u32* g = (const AS1 u32*)(xbf + (size_t)mt * 32768);
        AS3 u32* lb = (AS3 u32*)sA;
        #pragma unroll
        for (int i = 0; i < 16; ++i)
            __builtin_amdgcn_global_load_lds(g + (size_t)(i * 256 + tid) * 4,
                                             lb + (i * 256 + w * 64) * 4, 16, 0, 0);
    }

    float rowmin_reg[4][4];
    #pragma unroll
    for (int i = 0; i < 4; ++i)
        #pragma unroll
        for (int r = 0; r < 4; ++r) rowmin_reg[i][r] = 1e30f;

    for (int nt = t0; nt < t1; ++nt) {
        const u16* Bsrc = xtbf + (size_t)nt * 32768;
        // stage B kstep 0 into buf0
        {
            const AS1 u32* g = (const AS1 u32*)Bsrc;
            AS3 u32* lb = (AS3 u32*)sB[0];
            __builtin_amdgcn_global_load_lds(g + (size_t)tid * 4,        lb + (w * 64) * 4,       16, 0, 0);
            __builtin_amdgcn_global_load_lds(g + (size_t)(256 + tid) * 4, lb + (256 + w * 64) * 4, 16, 0, 0);
        }
        f32x4 acc[4][4];
        #pragma unroll
        for (int i = 0; i < 4; ++i)
            #pragma unroll
            for (int c = 0; c < 4; ++c)
                #pragma unroll
                for (int r = 0; r < 4; ++r) acc[i][c][r] = 0.f;

        __syncthreads();   // A (first tile) + B0 staged

        #pragma unroll
        for (int ks = 0; ks < 8; ++ks) {
            const int cur = ks & 1;
            if (ks < 7) {  // prefetch next kstep into the other buffer
                const AS1 u32* g = (const AS1 u32*)(Bsrc + (ks + 1) * 4096);
                AS3 u32* lb = (AS3 u32*)sB[cur ^ 1];
                __builtin_amdgcn_global_load_lds(g + (size_t)tid * 4,        lb + (w * 64) * 4,       16, 0, 0);
                __builtin_amdgcn_global_load_lds(g + (size_t)(256 + tid) * 4, lb + (256 + w * 64) * 4, 16, 0, 0);
            }
            bf16x8 af[4], bfr[4];
            #pragma unroll
            for (int i = 0; i < 4; ++i)
                af[i] = *(const bf16x8*)&sA[((ks * 8 + mq * 4 + i) * 64 + L) * 8];
            #pragma unroll
            for (int c = 0; c < 4; ++c)
                bfr[c] = *(const bf16x8*)&sB[cur][((nq * 4 + c) * 64 + L) * 8];
            #pragma unroll
            for (int i = 0; i < 4; ++i)
                #pragma unroll
                for (int c = 0; c < 4; ++c)
                    acc[i][c] = __builtin_amdgcn_mfma_f32_16x16x32_bf16(af[i], bfr[c], acc[i][c], 0, 0, 0);
            __syncthreads();  // drains prefetch (vmcnt) + protects buffer reuse
        }

        // ---- epilogue: scores, running min, margin capture ----
        const int colb = nt * 128 + nq * 64 + (L & 15);
        float t2v[4];
        #pragma unroll
        for (int c = 0; c < 4; ++c) t2v[c] = t2[colb + c * 16];

        float r4[4][4];   // per (msub, reg): min over the 4 n-subtiles
        #pragma unroll
        for (int i = 0; i < 4; ++i) {
            #pragma unroll
            for (int r = 0; r < 4; ++r) r4[i][r] = 1e30f;
            #pragma unroll
            for (int c = 0; c < 4; ++c)
                #pragma unroll
                for (int r = 0; r < 4; ++r)
                    r4[i][r] = fminf(r4[i][r], fmaf(-2.f, acc[i][c][r], t2v[c]));
        }

        if (nt == t0) {   // seed: exact tile row-min via 16-lane butterfly, publish
            float rr[4][4];
            #pragma unroll
            for (int i = 0; i < 4; ++i)
                #pragma unroll
                for (int r = 0; r < 4; ++r) rr[i][r] = r4[i][r];
            #pragma unroll
            for (int st = 1; st <= 8; st <<= 1)
                #pragma unroll
                for (int i = 0; i < 4; ++i)
                    #pragma unroll
                    for (int r = 0; r < 4; ++r)
                        rr[i][r] = fminf(rr[i][r], __shfl_xor(rr[i][r], st, 64));
            #pragma unroll
            for (int i = 0; i < 4; ++i)
                #pragma unroll
                for (int r = 0; r < 4; ++r) rowmin_reg[i][r] = rr[i][r];
            if ((L & 15) == 0) {
                #pragma unroll
                for (int i = 0; i < 4; ++i)
                    #pragma unroll
                    for (int r = 0; r < 4; ++r)
                        atomicMin(&rowminU[mt * 128 + mq * 64 + i * 16 + (L >> 4) * 4 + r],
                                  ordf(rr[i][r]));
            }
        }

        float thr[4][4];
        bool anyhit = false;
        #pragma unroll
        for (int i = 0; i < 4; ++i) {
            const int mrow = mt * 128 + mq * 64 + i * 16 + (L >> 4) * 4;
            uint4 gm = *(const uint4*)&rowminU[mrow];   // stale-OK (only loosens)
            u32 gmv[4] = {gm.x, gm.y, gm.z, gm.w};
            #pragma unroll
            for (int r = 0; r < 4; ++r) {
                float v = fminf(fminf(rowmin_reg[i][r], r4[i][r]), unordf(gmv[r]));
                rowmin_reg[i][r] = v;
                thr[i][r] = v + MARGIN;
                anyhit = anyhit || (r4[i][r] < thr[i][r]);
            }
        }
        if (__any(anyhit)) {   // rare wave-level slow path
            #pragma unroll
            for (int i = 0; i < 4; ++i) {
                #pragma unroll
                for (int r = 0; r < 4; ++r) {
                    if (r4[i][r] < thr[i][r]) {
                        const int q = mt * 128 + mq * 64 + i * 16 + (L >> 4) * 4 + r;
                        #pragma unroll
                        for (int c = 0; c < 4; ++c) {
                            float s = fmaf(-2.f, acc[i][c][r], t2v[c]);
                            if (s < thr[i][r]) {
                                int n = colb + c * 16;
                                u32 idx = atomicAdd(cand_cnt, 1u);
                                if (idx < CAND_CAP) cands[idx] = ((u32)q << 16) | (u32)n;
                                atomicMin(&rowminU[q], ordf(s));
                            }
                        }
                    }
                }
            }
        }
    }
}

// ---------------- exact fp32 rescore of captured candidates, one wave each ----------------
__global__ void rescore(const float* __restrict__ x, const float* __restrict__ Xt,
                        const float* __restrict__ t2, const u32* __restrict__ cand_cnt,
                        const u32* __restrict__ cands, u64* __restrict__ best) {
    const int L = threadIdx.x & 63;
    const int wid = blockIdx.x * (blockDim.x >> 6) + (threadIdx.x >> 6);
    const int nw = gridDim.x * (blockDim.x >> 6);
    u32 cnt = *cand_cnt;
    if (cnt > CAND_CAP) cnt = CAND_CAP;
    for (u32 idx = wid; idx < cnt; idx += nw) {
        u32 u = cands[idx];
        int q = (int)(u >> 16), n = (int)(u & 0xFFFFu);
        float4 xv = *(const float4*)(x  + (size_t)q * F_DIM + L * 4);
        float4 tv = *(const float4*)(Xt + (size_t)n * F_DIM + L * 4);
        float d = fmaf(xv.x, tv.x, fmaf(xv.y, tv.y, fmaf(xv.z, tv.z, xv.w * tv.w)));
        #pragma unroll
        for (int st = 32; st > 0; st >>= 1) d += __shfl_xor(d, st, 64);
        if (L == 0) {
            float s = fmaf(-2.f, d, t2[n]);
            u64 p = ((u64)ordf(s) << 32) | (u32)n;
            atomicMin(&best[q], p);
        }
    }
}

// ---------------- gather Y[nearest] ----------------
__global__ void gather_kernel(const float* __restrict__ Y, const u64* __restrict__ best,
                              float* __restrict__ out, int B, int N) {
    int gid = blockIdx.x * blockDim.x + threadIdx.x;
    int total = B * O_DIM;
    if (gid >= total) return;
    int b = gid / O_DIM;
    int o = gid - b * O_DIM;
    u32 n = (u32)(best[b] & 0xFFFFFFFFull);
    if (n >= (u32)N) n = 0;   // defensive
    out[gid] = Y[(size_t)n * O_DIM + o];
}

// ================= fp32 fallback (proven Round-1 path, used if ws too small) =================
#define BM 128
#define BN 128
#define BK 16
#define NSPLIT 64
#define LDA (BM + 4)

__global__ __launch_bounds__(256) void knn_main_fp32(
    const float* __restrict__ Xq, const float* __restrict__ Xt,
    const float* __restrict__ t2, u64* __restrict__ best, int N)
{
    __shared__ float As[BK][LDA];
    __shared__ float Bs[BK][LDA];
    __shared__ u64 red[BM][17];

    const int tid = threadIdx.x;
    const int tx = tid & 15;
    const int ty = tid >> 4;
    const int m0 = blockIdx.y * BM;
    const int CHUNK = (N + NSPLIT - 1) / NSPLIT;
    const int n0c = blockIdx.x * CHUNK;
    const int n1c = min(N, n0c + CHUNK);

    u64 bestv[8];
    #pragma unroll
    for (int i = 0; i < 8; ++i) bestv[i] = ~0ull;

    const int srow = tid >> 2;
    const int scol4 = (tid & 3) * 4;

    for (int nt = n0c; nt < n1c; nt += BN) {
        float accl[8][8];
        #pragma unroll
        for (int i = 0; i < 8; ++i)
            #pragma unroll
            for (int j = 0; j < 8; ++j) accl[i][j] = 0.f;
        for (int k0 = 0; k0 < F_DIM; k0 += BK) {
            #pragma unroll
            for (int h = 0; h < 2; ++h) {
                int row = h * 64 + srow;
                float4 av = *(const float4*)(Xq + (size_t)(m0 + row) * F_DIM + k0 + scol4);
                As[scol4 + 0][row] = av.x; As[scol4 + 1][row] = av.y;
                As[scol4 + 2][row] = av.z; As[scol4 + 3][row] = av.w;
                int n = nt + row;
                float4 bv = make_float4(0.f, 0.f, 0.f, 0.f);
                if (n < n1c) bv = *(const float4*)(Xt + (size_t)n * F_DIM + k0 + scol4);
                Bs[scol4 + 0][row] = bv.x; Bs[scol4 + 1][row] = bv.y;
                Bs[scol4 + 2][row] = bv.z; Bs[scol4 + 3][row] = bv.w;
            }
            __syncthreads();
            #pragma unroll
            for (int k = 0; k < BK; ++k) {
                float4 a0 = *(const float4*)&As[k][ty * 4];
                float4 a1 = *(const float4*)&As[k][64 + ty * 4];
                float4 b0 = *(const float4*)&Bs[k][tx * 4];
                float4 b1 = *(const float4*)&Bs[k][64 + tx * 4];
                float am[8] = {a0.x, a0.y, a0.z, a0.w, a1.x, a1.y, a1.z, a1.w};
                float bn[8] = {b0.x, b0.y, b0.z, b0.w, b1.x, b1.y, b1.z, b1.w};
                #pragma unroll
                for (int i = 0; i < 8; ++i)
                    #pragma unroll
                    for (int j = 0; j < 8; ++j)
                        accl[i][j] = fmaf(am[i], bn[j], accl[i][j]);
            }
            __syncthreads();
        }
        #pragma unroll
        for (int j = 0; j < 8; ++j) {
            int nl = (j < 4) ? (tx * 4 + j) : (64 + tx * 4 + (j - 4));
            int n = nt + nl;
            if (n < n1c) {
                float t2v = t2[n];
                #pragma unroll
                for (int i = 0; i < 8; ++i) {
                    float score = fmaf(-2.f, accl[i][j], t2v);
                    u64 p = ((u64)ordf(score) << 32) | (u32)n;
                    bestv[i] = (p < bestv[i]) ? p : bestv[i];
                }
            }
        }
    }
    #pragma unroll
    for (int i = 0; i < 8; ++i) {
        int ml = (i < 4) ? (ty * 4 + i) : (64 + ty * 4 + (i - 4));
        red[ml][tx] = bestv[i];
    }
    __syncthreads();
    if (tid < BM) {
        u64 b = red[tid][0];
        #pragma unroll
        for (int t = 1; t < 16; ++t) { u64 v = red[tid][t]; b = (v < b) ? v : b; }
        atomicMin(&best[m0 + tid], b);
    }
}

// ================= launch =================
extern "C" void kernel_launch(void* const* d_in, const int* in_sizes, int n_in,
                              void* d_out, int out_size, void* d_ws, size_t ws_size,
                              hipStream_t stream) {
    const float* x  = (const float*)d_in[0];
    const float* Xt = (const float*)d_in[1];
    const float* Yt = (const float*)d_in[2];
    float* out = (float*)d_out;

    const int B = in_sizes[0] / F_DIM;        // 2048
    const int N = in_sizes[1] / F_DIM;        // 50000
    const int NT = (N + 127) / 128;           // 391
    const int Npad = NT * 128;                // 50048
    const int MT = B / 128;                   // 16
    const int TPC = 13;
    const int NCH = (NT + TPC - 1) / TPC;     // 31

    char* wsp = (char*)d_ws;
    size_t off = 0;
    auto nxt = [&](size_t bytes) {
        char* p = wsp + off;
        off = (off + bytes + 255) & ~(size_t)255;
        return p;
    };
    float* t2      = (float*)nxt((size_t)Npad * 4);
    u32*   rowmin  = (u32*)  nxt((size_t)B * 4);
    u64*   best    = (u64*)  nxt((size_t)B * 8);
    u32*   cnt     = (u32*)  nxt(256);
    u32*   cands   = (u32*)  nxt((size_t)CAND_CAP * 4);
    u16*   xbf     = (u16*)  nxt((size_t)B * F_DIM * 2);
    u16*   xtbf    = (u16*)  nxt((size_t)Npad * F_DIM * 2);
    size_t required = off;

    init_kernel<<<(B + 255) / 256, 256, 0, stream>>>(best, rowmin, cnt, B);

    if (ws_size >= required && B % 128 == 0) {
        // fast path: bf16 MFMA + exact margin-rescue
        t2_kernel<<<(Npad + 3) / 4, 256, 0, stream>>>(Xt, t2, N, Npad);
        int unitsA = MT * 4096;
        convert_swizzle<<<(unitsA + 255) / 256, 256, 0, stream>>>(x, xbf, B, unitsA);
        int unitsB = NT * 4096;
        convert_swizzle<<<(unitsB + 255) / 256, 256, 0, stream>>>(Xt, xtbf, N, unitsB);
        knn_mfma<<<dim3(MT, NCH), 256, 0, stream>>>(xbf, xtbf, t2, rowmin, cnt, cands, NT, TPC);
        rescore<<<512, 256, 0, stream>>>(x, Xt, t2, cnt, cands, best);
    } else {
        // fallback: proven fp32 VALU path
        t2_kernel<<<(N + 3) / 4, 256, 0, stream>>>(Xt, t2, N, N);
        dim3 grid(NSPLIT, B / BM);
        knn_main_fp32<<<grid, 256, 0, stream>>>(x, Xt, t2, best, N);
    }

    int total = B * O_DIM;
    gather_kernel<<<(total + 255) / 256, 256, 0, stream>>>(Yt, best, out, B, N);
}